// Round 3
// baseline (104.486 us; speedup 1.0000x reference)
//
#include <hip/hip_runtime.h>
#include <math.h>

#define B_ 32
#define N_ 2048
#define M_ 16
#define K_ 32
#define EPS 1e-12f

constexpr int KS      = 8;           // k-slices (blocks per batch)
constexpr int KPB     = K_ / KS;     // 4 k-values per block
constexpr int NC      = 128;         // rows per chunk
constexpr int NCHUNK  = N_ / NC;     // 16
constexpr int THREADS = 512;         // 8 waves: thread = (grp 0..127) x (k_local 0..3)
constexpr int YSTRIDE = 20;          // padded row stride (80 B, 16B-aligned, breaks pow2 banks)

// ---------------- kernel 1: fused validity-scan + accumulation ----------------
// Block (slice, b) computes G[b, slice*KPB .. slice*KPB+3, :] =
//   sum_n w[b,n]*coef[b,n,k]*y[b,n,m]
// Validity prefix (cumprod) is derived in-block: rows are processed in
// ascending n, so a running first-invalid `fi` is exact. No atomics: each
// G element has exactly one writer, so no zero-init either.
__global__ __launch_bounds__(THREADS) void pml_fused_kernel(
    const float* __restrict__ dgm, const float* __restrict__ theta,
    const float* __restrict__ class_w, float* __restrict__ G)
{
    __shared__ __align__(16) float y_lds[NC * YSTRIDE];  // 10 KB
    __shared__ float hom_lds[NC];
    __shared__ unsigned wred[8];
    __shared__ float red[8][KPB][M_];                    // 2 KB

    const int b       = blockIdx.y;
    const int slice   = blockIdx.x;
    const int tid     = threadIdx.x;
    const int k_local = tid & (KPB - 1);
    const int grp     = tid >> 2;          // 0..127: row within chunk
    const int lane    = tid & 63;
    const int wv      = tid >> 6;          // 0..7
    const int k       = slice * KPB + k_local;

    // theta row for this thread's k
    float th[M_], t2[M_];
#pragma unroll
    for (int m = 0; m < M_; ++m) { th[m] = theta[k * M_ + m]; t2[m] = th[m] * th[m]; }

    float g[M_];
#pragma unroll
    for (int m = 0; m < M_; ++m) g[m] = 0.0f;

    const float cw0 = class_w[0], cw1 = class_w[1];
    const float* base = dgm + (size_t)b * N_ * (M_ + 1);

    unsigned fi = N_;   // first invalid n (exclusive end of valid prefix)

    for (int c = 0; c < NCHUNK; ++c) {
        const unsigned n0 = (unsigned)(c * NC);
        if (n0 >= fi) break;              // fi is block-uniform -> uniform break
        __syncthreads();                  // protect y_lds/wred reuse across chunks

        // stage chunk: NC*17 contiguous floats, split hom / y(padded)
        const float* src = base + n0 * (M_ + 1);
        for (int i = tid; i < NC * (M_ + 1); i += THREADS) {
            float v = src[i];
            int nl = i / (M_ + 1);
            int j  = i - nl * (M_ + 1);
            if (j == 0) hom_lds[nl] = v;
            else        y_lds[nl * YSTRIDE + (j - 1)] = v;
        }
        __syncthreads();

        // load my row (4 threads per row, broadcast reads)
        const float4* yv = (const float4*)(y_lds + grp * YSTRIDE);
        float4 a0 = yv[0], a1 = yv[1], a2 = yv[2], a3 = yv[3];
        float h = hom_lds[grp];

        bool nz = (h != 0.0f) |
                  (a0.x != 0.0f) | (a0.y != 0.0f) | (a0.z != 0.0f) | (a0.w != 0.0f) |
                  (a1.x != 0.0f) | (a1.y != 0.0f) | (a1.z != 0.0f) | (a1.w != 0.0f) |
                  (a2.x != 0.0f) | (a2.y != 0.0f) | (a2.z != 0.0f) | (a2.w != 0.0f) |
                  (a3.x != 0.0f) | (a3.y != 0.0f) | (a3.z != 0.0f) | (a3.w != 0.0f);
        bool ok = ((int)h <= 1) && nz;

        // block-wide first-invalid row of this chunk
        unsigned long long bal = __ballot(!ok);
        if (lane == 0)
            wred[wv] = bal ? (unsigned)(wv * 16 + ((__ffsll((long long)bal) - 1) >> 2))
                           : 0xFFFFFFFFu;
        __syncthreads();
        unsigned mn = 0xFFFFFFFFu;
#pragma unroll
        for (int q = 0; q < 8; ++q) mn = min(mn, wred[q]);
        if (mn != 0xFFFFFFFFu) fi = min(fi, n0 + mn);

        // weight for my row (0 past the valid prefix)
        float w = 0.0f;
        if (n0 + (unsigned)grp < fi) {
            int hc = min(max((int)h, 0), 1);
            w = hc ? cw1 : cw0;
        }

        float y[M_] = { a0.x, a0.y, a0.z, a0.w,  a1.x, a1.y, a1.z, a1.w,
                        a2.x, a2.y, a2.z, a2.w,  a3.x, a3.y, a3.z, a3.w };
        float s = 0.0f;
#pragma unroll
        for (int m = 0; m < M_; ++m) s = fmaf(y[m] * y[m], t2[m], s);
        float d  = 1.0f + sqrtf(1.0f + s + EPS);
        float xn = sqrtf(s / (d * d) + EPS);
        float xc = fminf(xn, 1.0f - 1e-5f);
        float wc = w * (atanhf(xc) / (xn * d));
#pragma unroll
        for (int m = 0; m < M_; ++m) g[m] = fmaf(wc, y[m], g[m]);
    }

    // reduce g over the 16 grps within each wave (offsets multiple of 4 keep k_local)
#pragma unroll
    for (int off = 32; off >= 4; off >>= 1) {
#pragma unroll
        for (int m = 0; m < M_; ++m) g[m] += __shfl_down(g[m], off, 64);
    }
    if (lane < KPB) {
#pragma unroll
        for (int m = 0; m < M_; ++m) red[wv][lane][m] = g[m];
    }
    __syncthreads();

    // final sum over 8 waves; one writer per G element, coalesced 64-float store
    if (tid < KPB * M_) {
        int kl = tid >> 4, m = tid & 15;
        float ssum = 0.0f;
#pragma unroll
        for (int q = 0; q < 8; ++q) ssum += red[q][kl][m];
        G[((size_t)b * K_ + slice * KPB + kl) * M_ + m] = ssum;
    }
}

// ---------------- kernel 2: epilogue (2 batches per 64-thread block) ----------------
__global__ void pml_epilogue_kernel(const float* __restrict__ G,
                                    const float* __restrict__ theta,
                                    float* __restrict__ out) {
    int b    = blockIdx.x * 2 + (threadIdx.x >> 5);
    int lane = threadIdx.x & 31;               // = k
    const float* Gb = G + (size_t)b * K_ * M_;

    float S[M_];
#pragma unroll
    for (int m = 0; m < M_; ++m)
        S[m] = theta[lane * M_ + m] * Gb[lane * M_ + m];

    // inclusive prefix sum over k (width-32 segments keep batches separate)
#pragma unroll
    for (int m = 0; m < M_; ++m) {
        float v = S[m];
#pragma unroll
        for (int off = 1; off < K_; off <<= 1) {
            float up = __shfl_up(v, off, 32);
            if (lane >= off) v += up;
        }
        S[m] = v;
    }

    float sn2 = 0.0f;
#pragma unroll
    for (int m = 0; m < M_; ++m) sn2 = fmaf(S[m], S[m], sn2);
    float Sn = sqrtf(sn2 + EPS);
    float r = tanhf(Sn) / Sn;

    float xd[M_];
    float xdn2 = 0.0f;
#pragma unroll
    for (int m = 0; m < M_; ++m) { xd[m] = r * S[m]; xdn2 = fmaf(xd[m], xd[m], xdn2); }
    float scale = 2.0f / fmaxf(1.0f - xdn2, 1e-7f);

#pragma unroll
    for (int m = 0; m < M_; ++m)
        out[(size_t)b * (K_ * M_) + lane * M_ + m] = scale * xd[m];
}

extern "C" void kernel_launch(void* const* d_in, const int* in_sizes, int n_in,
                              void* d_out, int out_size, void* d_ws, size_t ws_size,
                              hipStream_t stream) {
    const float* dgm     = (const float*)d_in[0];   // (B, N, 17)
    const float* theta   = (const float*)d_in[1];   // (K, M)
    const float* class_w = (const float*)d_in[2];   // (2,)
    float* out = (float*)d_out;                     // (B, K*M) f32

    float* G = (float*)d_ws;   // B*K*M floats; every element written by kernel 1

    dim3 grid(KS, B_);
    pml_fused_kernel<<<grid, THREADS, 0, stream>>>(dgm, theta, class_w, G);

    pml_epilogue_kernel<<<B_ / 2, 64, 0, stream>>>(G, theta, out);
}

// Round 4
// 84.578 us; speedup vs baseline: 1.2354x; 1.2354x over previous
//
#include <hip/hip_runtime.h>
#include <math.h>

#define B_ 32
#define N_ 2048
#define M_ 16
#define K_ 32
#define EPS 1e-12f

constexpr int NC      = 128;          // rows per chunk
constexpr int NCHUNK  = N_ / NC;      // 16
constexpr int THREADS = 256;          // thread = (k 0..31) x (grp 0..7); 16 rows/thread
constexpr int YSTRIDE = 20;           // padded row stride: 80 B, 16B-aligned, non-pow2

// ---------------- kernel 1: per-chunk accumulation + local validity ----------------
// Block (c, b): stages its 128-row chunk once, finds the chunk-local first
// invalid row (validity is a cumprod prefix, so the global mask restricted to
// this chunk is either all-off (decided by earlier chunks -> epilogue drops the
// whole partial) or exactly the local prefix). Writes
//   G_part[b][c][k][m] = sum_{nl < local_mn} w * coef * y     (no atomics)
//   finv_loc[b][c]     = local first-invalid row (NC if none)
__global__ __launch_bounds__(THREADS) void pml_main_kernel(
    const float* __restrict__ dgm, const float* __restrict__ theta,
    const float* __restrict__ class_w,
    float* __restrict__ G_part, unsigned* __restrict__ finv_loc)
{
    __shared__ __align__(16) float y_lds[NC * YSTRIDE];  // 10 KB
    __shared__ float hom_lds[NC];
    __shared__ float w_lds[NC];
    __shared__ unsigned wred[2];
    __shared__ float red[4][K_ * (M_ + 1)];              // 8.5 KB, stride-17 (bank-spread)

    const int b    = blockIdx.y;
    const int c    = blockIdx.x;
    const int n0   = c * NC;
    const int tid  = threadIdx.x;
    const int k    = tid & (K_ - 1);
    const int grp  = tid >> 5;        // 0..7
    const int lane = tid & 63;
    const int wv   = tid >> 6;        // 0..3

    // ---- stage chunk (2176 contiguous floats, coalesced scalar loads) ----
    const float* src = dgm + ((size_t)b * N_ + n0) * (M_ + 1);
    for (int i = tid; i < NC * (M_ + 1); i += THREADS) {
        float v  = src[i];
        int   nl = i / (M_ + 1);
        int   j  = i - nl * (M_ + 1);
        if (j == 0) hom_lds[nl] = v;
        else        y_lds[nl * YSTRIDE + (j - 1)] = v;
    }
    __syncthreads();

    // ---- local validity scan: threads 0..127 each check one row ----
    const float cw0 = class_w[0], cw1 = class_w[1];
    if (tid < NC) {
        const float4* yv = (const float4*)(y_lds + tid * YSTRIDE);
        float4 a0 = yv[0], a1 = yv[1], a2 = yv[2], a3 = yv[3];
        float  h  = hom_lds[tid];
        bool nz = (h != 0.0f) |
                  (a0.x != 0.0f) | (a0.y != 0.0f) | (a0.z != 0.0f) | (a0.w != 0.0f) |
                  (a1.x != 0.0f) | (a1.y != 0.0f) | (a1.z != 0.0f) | (a1.w != 0.0f) |
                  (a2.x != 0.0f) | (a2.y != 0.0f) | (a2.z != 0.0f) | (a2.w != 0.0f) |
                  (a3.x != 0.0f) | (a3.y != 0.0f) | (a3.z != 0.0f) | (a3.w != 0.0f);
        bool ok = ((int)h <= 1) && nz;
        // waves 0,1 fully active here (tid<128) -> ballot is well-defined
        unsigned long long bal = __ballot(!ok);
        if (lane == 0)
            wred[wv] = bal ? (unsigned)(wv * 64 + (__ffsll((long long)bal) - 1))
                           : 0xFFFFFFFFu;
        // weight as if valid; rows >= local_mn are simply never read
        int hc = min(max((int)h, 0), 1);
        w_lds[tid] = hc ? cw1 : cw0;
    }
    __syncthreads();
    const int local_mn = (int)min(min(wred[0], wred[1]), (unsigned)NC);

    // ---- per-thread accumulation over rows grp, grp+8, ... < local_mn ----
    float t2[M_];
#pragma unroll
    for (int m = 0; m < M_; ++m) { float t = theta[k * M_ + m]; t2[m] = t * t; }
    float g[M_];
#pragma unroll
    for (int m = 0; m < M_; ++m) g[m] = 0.0f;

    for (int nl = grp; nl < local_mn; nl += 8) {
        float w = w_lds[nl];                                  // 2 addrs/wave: free
        const float4* yv = (const float4*)(y_lds + nl * YSTRIDE);  // 2 rows/wave: free
        float4 a0 = yv[0], a1 = yv[1], a2 = yv[2], a3 = yv[3];
        float y[M_] = { a0.x, a0.y, a0.z, a0.w,  a1.x, a1.y, a1.z, a1.w,
                        a2.x, a2.y, a2.z, a2.w,  a3.x, a3.y, a3.z, a3.w };
        float s = 0.0f;
#pragma unroll
        for (int m = 0; m < M_; ++m) s = fmaf(y[m] * y[m], t2[m], s);
        float d  = 1.0f + sqrtf(1.0f + s + EPS);
        float xn = sqrtf(s / (d * d) + EPS);
        float xc = fminf(xn, 1.0f - 1e-5f);
        float wc = w * (atanhf(xc) / (xn * d));
#pragma unroll
        for (int m = 0; m < M_; ++m) g[m] = fmaf(wc, y[m], g[m]);
    }

    // ---- reduce: lanes (k, k+32) within each wave, then 4 waves via LDS ----
#pragma unroll
    for (int m = 0; m < M_; ++m) g[m] += __shfl_down(g[m], 32, 64);
    if (lane < K_) {
#pragma unroll
        for (int m = 0; m < M_; ++m) red[wv][lane * (M_ + 1) + m] = g[m];
    }
    __syncthreads();

    float* dst = G_part + (((size_t)b * NCHUNK + c) * K_ * M_);
    for (int p = tid; p < K_ * M_; p += THREADS) {
        int kk = p >> 4, m = p & 15;
        int idx = kk * (M_ + 1) + m;
        dst[p] = red[0][idx] + red[1][idx] + red[2][idx] + red[3][idx];
    }
    if (tid == 0) finv_loc[b * NCHUNK + c] = (unsigned)local_mn;
}

// ---------------- kernel 2: epilogue (one block per batch) ----------------
__global__ __launch_bounds__(256) void pml_epilogue_kernel(
    const float* __restrict__ G_part, const unsigned* __restrict__ finv_loc,
    const float* __restrict__ theta, float* __restrict__ out)
{
    __shared__ float S_lds[K_ * M_];
    __shared__ unsigned fl[NCHUNK];

    const int b   = blockIdx.x;
    const int tid = threadIdx.x;

    if (tid < NCHUNK) fl[tid] = finv_loc[b * NCHUNK + tid];
    __syncthreads();

    // include chunks 0..c* where c* is the first chunk with a local invalid
    int ninc = NCHUNK;
    for (int cc = 0; cc < NCHUNK; ++cc) {
        if (fl[cc] < (unsigned)NC) { ninc = cc + 1; break; }
    }

    // sum included per-chunk partials (coalesced; G_part is L2-hot)
    const float* Gb = G_part + (size_t)b * NCHUNK * K_ * M_;
    for (int e = tid; e < K_ * M_; e += 256) {
        float s = 0.0f;
        for (int cc = 0; cc < ninc; ++cc) s += Gb[cc * (K_ * M_) + e];
        S_lds[e] = s;
    }
    __syncthreads();

    if (tid < K_) {   // wave 0, lanes 0..31; lane = k
        const int lane = tid;
        float S[M_];
#pragma unroll
        for (int m = 0; m < M_; ++m)
            S[m] = theta[lane * M_ + m] * S_lds[lane * M_ + m];

        // inclusive prefix sum over k within the 32-lane segment
#pragma unroll
        for (int m = 0; m < M_; ++m) {
            float v = S[m];
#pragma unroll
            for (int off = 1; off < K_; off <<= 1) {
                float up = __shfl_up(v, off, 32);
                if (lane >= off) v += up;
            }
            S[m] = v;
        }

        float sn2 = 0.0f;
#pragma unroll
        for (int m = 0; m < M_; ++m) sn2 = fmaf(S[m], S[m], sn2);
        float Sn = sqrtf(sn2 + EPS);
        float r  = tanhf(Sn) / Sn;

        float xd[M_];
        float xdn2 = 0.0f;
#pragma unroll
        for (int m = 0; m < M_; ++m) { xd[m] = r * S[m]; xdn2 = fmaf(xd[m], xd[m], xdn2); }
        float scale = 2.0f / fmaxf(1.0f - xdn2, 1e-7f);

#pragma unroll
        for (int m = 0; m < M_; ++m)
            out[(size_t)b * (K_ * M_) + lane * M_ + m] = scale * xd[m];
    }
}

extern "C" void kernel_launch(void* const* d_in, const int* in_sizes, int n_in,
                              void* d_out, int out_size, void* d_ws, size_t ws_size,
                              hipStream_t stream) {
    const float* dgm     = (const float*)d_in[0];   // (B, N, 17)
    const float* theta   = (const float*)d_in[1];   // (K, M)
    const float* class_w = (const float*)d_in[2];   // (2,)
    float* out = (float*)d_out;                     // (B, K*M) f32

    // ws layout: G_part [B][NCHUNK][K][M] floats, then finv_loc [B*NCHUNK] uints.
    // Every element is written by kernel 1 before being read -> no init needed.
    float*    G_part   = (float*)d_ws;
    unsigned* finv_loc = (unsigned*)((char*)d_ws +
                         (size_t)B_ * NCHUNK * K_ * M_ * sizeof(float));

    dim3 grid(NCHUNK, B_);
    pml_main_kernel<<<grid, THREADS, 0, stream>>>(dgm, theta, class_w, G_part, finv_loc);

    pml_epilogue_kernel<<<B_, 256, 0, stream>>>(G_part, finv_loc, theta, out);
}

// Round 5
// 76.251 us; speedup vs baseline: 1.3703x; 1.1092x over previous
//
#include <hip/hip_runtime.h>
#include <math.h>

#define B_ 32
#define N_ 2048
#define M_ 16
#define K_ 32
#define EPS 1e-12f

constexpr int NC      = 128;          // rows per chunk
constexpr int NCHUNK  = N_ / NC;      // 16
constexpr int THREADS = 256;          // thread = (k 0..31) x (grp 0..7); 16 rows/thread
constexpr int YSTRIDE = 20;           // padded row stride: 80 B, 16B-aligned, non-pow2

// fast atanh: 0.5*ln((1+x)/(1-x)); x in [0, 1-1e-5] -> rcp arg >= 1e-5, safe.
// v_log_f32 (~1 ULP log2) + v_rcp_f32 (~1 ULP). 0.34657359 = 0.5*ln(2).
__device__ __forceinline__ float fast_atanh(float x) {
    float ratio = (1.0f + x) * __builtin_amdgcn_rcpf(1.0f - x);
    return 0.34657359f * __log2f(ratio);
}

// ---------------- kernel 1: per-chunk accumulation + local validity ----------------
// Block (c, b): stages its 128-row chunk once, finds the chunk-local first
// invalid row (validity is a cumprod prefix: the global mask restricted to this
// chunk is either all-off — decided by earlier chunks, epilogue drops the whole
// partial — or exactly the local prefix). Writes
//   G_part[b][c][k][m] = sum_{nl < local_mn} w * coef * y     (no atomics)
//   finv_loc[b][c]     = local first-invalid row (NC if none)
__global__ __launch_bounds__(THREADS) void pml_main_kernel(
    const float* __restrict__ dgm, const float* __restrict__ theta,
    const float* __restrict__ class_w,
    float* __restrict__ G_part, unsigned* __restrict__ finv_loc)
{
    __shared__ __align__(16) float y_lds[NC * YSTRIDE];  // 10 KB
    __shared__ float hom_lds[NC];
    __shared__ float w_lds[NC];
    __shared__ unsigned wred[2];
    __shared__ float red[4][K_ * (M_ + 1)];              // 8.5 KB, stride-17 (bank-spread)

    const int b    = blockIdx.y;
    const int c    = blockIdx.x;
    const int tid  = threadIdx.x;
    const int k    = tid & (K_ - 1);
    const int grp  = tid >> 5;        // 0..7
    const int lane = tid & 63;
    const int wv   = tid >> 6;        // 0..3

    // ---- stage chunk: 2176 contiguous floats = 544 float4 (16B-aligned:
    // chunk offset = 2176*c*4 B, base = b*2048*17*4 B, both /16) ----
    const float4* src4 = (const float4*)(dgm + ((size_t)b * N_ + c * NC) * (M_ + 1));
    for (int i4 = tid; i4 < NC * (M_ + 1) / 4; i4 += THREADS) {
        float4 v = src4[i4];
        int i  = i4 * 4;
        int nl = i / (M_ + 1);
        int j  = i - nl * (M_ + 1);
        float vv[4] = { v.x, v.y, v.z, v.w };
#pragma unroll
        for (int e = 0; e < 4; ++e) {
            if (j == 0) hom_lds[nl] = vv[e];
            else        y_lds[nl * YSTRIDE + (j - 1)] = vv[e];
            if (++j == M_ + 1) { j = 0; ++nl; }
        }
    }
    __syncthreads();

    // ---- local validity scan: threads 0..127 each check one row ----
    const float cw0 = class_w[0], cw1 = class_w[1];
    if (tid < NC) {
        const float4* yv = (const float4*)(y_lds + tid * YSTRIDE);
        float4 a0 = yv[0], a1 = yv[1], a2 = yv[2], a3 = yv[3];
        float  h  = hom_lds[tid];
        bool nz = (h != 0.0f) |
                  (a0.x != 0.0f) | (a0.y != 0.0f) | (a0.z != 0.0f) | (a0.w != 0.0f) |
                  (a1.x != 0.0f) | (a1.y != 0.0f) | (a1.z != 0.0f) | (a1.w != 0.0f) |
                  (a2.x != 0.0f) | (a2.y != 0.0f) | (a2.z != 0.0f) | (a2.w != 0.0f) |
                  (a3.x != 0.0f) | (a3.y != 0.0f) | (a3.z != 0.0f) | (a3.w != 0.0f);
        bool ok = ((int)h <= 1) && nz;
        // waves 0,1 fully active here (tid<128) -> ballot well-defined
        unsigned long long bal = __ballot(!ok);
        if (lane == 0)
            wred[wv] = bal ? (unsigned)(wv * 64 + (__ffsll((long long)bal) - 1))
                           : 0xFFFFFFFFu;
        // weight as if valid; rows >= local_mn are simply never read
        int hc = min(max((int)h, 0), 1);
        w_lds[tid] = hc ? cw1 : cw0;
    }
    __syncthreads();
    const int local_mn = (int)min(min(wred[0], wred[1]), (unsigned)NC);

    // ---- per-thread accumulation over rows grp, grp+8, ... < local_mn ----
    float t2[M_];
#pragma unroll
    for (int m = 0; m < M_; ++m) { float t = theta[k * M_ + m]; t2[m] = t * t; }
    float g[M_];
#pragma unroll
    for (int m = 0; m < M_; ++m) g[m] = 0.0f;

    for (int nl = grp; nl < local_mn; nl += 8) {
        float w = w_lds[nl];                                       // 2 addrs/wave: free
        const float4* yv = (const float4*)(y_lds + nl * YSTRIDE);  // 2 rows/wave: free
        float4 a0 = yv[0], a1 = yv[1], a2 = yv[2], a3 = yv[3];
        float y[M_] = { a0.x, a0.y, a0.z, a0.w,  a1.x, a1.y, a1.z, a1.w,
                        a2.x, a2.y, a2.z, a2.w,  a3.x, a3.y, a3.z, a3.w };
        float s = 0.0f;
#pragma unroll
        for (int m = 0; m < M_; ++m) s = fmaf(y[m] * y[m], t2[m], s);
        // d = 1+sqrt(1+un^2); xn^2 = s/d^2 + EPS; coef = atanh(min(xn,1-1e-5))/(xn*d)
        float d   = 1.0f + sqrtf(1.0f + s + EPS);
        float rd  = __builtin_amdgcn_rcpf(d);
        float xn2 = fmaf(s, rd * rd, EPS);
        float xn  = sqrtf(xn2);
        float inv_xnd = __builtin_amdgcn_rsqf(xn2) * rd;   // 1/(xn*d)
        float xc  = fminf(xn, 1.0f - 1e-5f);
        float wc  = w * (fast_atanh(xc) * inv_xnd);
#pragma unroll
        for (int m = 0; m < M_; ++m) g[m] = fmaf(wc, y[m], g[m]);
    }

    // ---- reduce: lanes (k, k+32) within each wave, then 4 waves via LDS ----
#pragma unroll
    for (int m = 0; m < M_; ++m) g[m] += __shfl_down(g[m], 32, 64);
    if (lane < K_) {
#pragma unroll
        for (int m = 0; m < M_; ++m) red[wv][lane * (M_ + 1) + m] = g[m];
    }
    __syncthreads();

    float* dst = G_part + (((size_t)b * NCHUNK + c) * K_ * M_);
    for (int p = tid; p < K_ * M_; p += THREADS) {
        int kk = p >> 4, m = p & 15;
        int idx = kk * (M_ + 1) + m;
        dst[p] = red[0][idx] + red[1][idx] + red[2][idx] + red[3][idx];
    }
    if (tid == 0) finv_loc[b * NCHUNK + c] = (unsigned)local_mn;
}

// ---------------- kernel 2: epilogue (one block per batch) ----------------
__global__ __launch_bounds__(256) void pml_epilogue_kernel(
    const float* __restrict__ G_part, const unsigned* __restrict__ finv_loc,
    const float* __restrict__ theta, float* __restrict__ out)
{
    __shared__ float S_lds[K_ * M_];
    __shared__ unsigned fl[NCHUNK];

    const int b   = blockIdx.x;
    const int tid = threadIdx.x;

    if (tid < NCHUNK) fl[tid] = finv_loc[b * NCHUNK + tid];
    __syncthreads();

    // include chunks 0..c* where c* is the first chunk with a local invalid
    int ninc = NCHUNK;
    for (int cc = 0; cc < NCHUNK; ++cc) {
        if (fl[cc] < (unsigned)NC) { ninc = cc + 1; break; }
    }

    // sum included per-chunk partials (coalesced; G_part is L2-hot)
    const float* Gb = G_part + (size_t)b * NCHUNK * K_ * M_;
    for (int e = tid; e < K_ * M_; e += 256) {
        float s = 0.0f;
        for (int cc = 0; cc < ninc; ++cc) s += Gb[cc * (K_ * M_) + e];
        S_lds[e] = s;
    }
    __syncthreads();

    if (tid < K_) {   // wave 0, lanes 0..31; lane = k
        const int lane = tid;
        float S[M_];
#pragma unroll
        for (int m = 0; m < M_; ++m)
            S[m] = theta[lane * M_ + m] * S_lds[lane * M_ + m];

        // inclusive prefix sum over k within the 32-lane segment
#pragma unroll
        for (int m = 0; m < M_; ++m) {
            float v = S[m];
#pragma unroll
            for (int off = 1; off < K_; off <<= 1) {
                float up = __shfl_up(v, off, 32);
                if (lane >= off) v += up;
            }
            S[m] = v;
        }

        float sn2 = 0.0f;
#pragma unroll
        for (int m = 0; m < M_; ++m) sn2 = fmaf(S[m], S[m], sn2);
        float Sn = sqrtf(sn2 + EPS);
        // tanh(Sn)/Sn via expf; Sn >= 1e-6 so no cancellation risk that matters
        float e2 = __expf(-2.0f * Sn);
        float r  = (1.0f - e2) * __builtin_amdgcn_rcpf((1.0f + e2) * Sn);

        float xd[M_];
        float xdn2 = 0.0f;
#pragma unroll
        for (int m = 0; m < M_; ++m) { xd[m] = r * S[m]; xdn2 = fmaf(xd[m], xd[m], xdn2); }
        float scale = 2.0f / fmaxf(1.0f - xdn2, 1e-7f);

#pragma unroll
        for (int m = 0; m < M_; ++m)
            out[(size_t)b * (K_ * M_) + lane * M_ + m] = scale * xd[m];
    }
}

extern "C" void kernel_launch(void* const* d_in, const int* in_sizes, int n_in,
                              void* d_out, int out_size, void* d_ws, size_t ws_size,
                              hipStream_t stream) {
    const float* dgm     = (const float*)d_in[0];   // (B, N, 17)
    const float* theta   = (const float*)d_in[1];   // (K, M)
    const float* class_w = (const float*)d_in[2];   // (2,)
    float* out = (float*)d_out;                     // (B, K*M) f32

    // ws layout: G_part [B][NCHUNK][K][M] floats, then finv_loc [B*NCHUNK] uints.
    // Every element is written by kernel 1 before being read -> no init needed.
    float*    G_part   = (float*)d_ws;
    unsigned* finv_loc = (unsigned*)((char*)d_ws +
                         (size_t)B_ * NCHUNK * K_ * M_ * sizeof(float));

    dim3 grid(NCHUNK, B_);
    pml_main_kernel<<<grid, THREADS, 0, stream>>>(dgm, theta, class_w, G_part, finv_loc);

    pml_epilogue_kernel<<<B_, 256, 0, stream>>>(G_part, finv_loc, theta, out);
}